// Round 7
// baseline (228.763 us; speedup 1.0000x reference)
//
#include <hip/hip_runtime.h>

typedef unsigned short u16;
typedef unsigned int u32;
typedef __attribute__((ext_vector_type(8))) short bf16x8;
typedef __attribute__((ext_vector_type(4))) float f32x4;
typedef __attribute__((ext_vector_type(8))) u16 u16x8;
typedef __attribute__((ext_vector_type(2))) u32 u32x2;

__device__ __forceinline__ u16 f2b(float f){
  u32 u = __float_as_uint(f);
  u32 r = (u + 0x7fffu + ((u >> 16) & 1u)) >> 16;
  return (u16)r;
}
__device__ __forceinline__ float b2f(u16 h){ return __uint_as_float(((u32)h) << 16); }
// packed f32x2 -> bf16x2 (RNE), lo=src0 hi=src1
__device__ __forceinline__ u32 cvt_pk_bf16(float lo, float hi){
  u32 r; asm("v_cvt_pk_bf16_f32 %0, %1, %2" : "=v"(r) : "v"(lo), "v"(hi)); return r;
}
// LDS-visibility barrier WITHOUT vmcnt drain (keeps global prefetches in flight)
__device__ __forceinline__ void lds_barrier(){
  asm volatile("s_waitcnt lgkmcnt(0)" ::: "memory");
  __builtin_amdgcn_s_barrier();
  asm volatile("" ::: "memory");
}

typedef const __attribute__((address_space(1))) void gvoid;
typedef __attribute__((address_space(3))) void svoid;
__device__ __forceinline__ void gl_lds16(const void* g, void* l){
  __builtin_amdgcn_global_load_lds((gvoid*)g, (svoid*)l, 16, 0, 0);
}

// ---------------- convert x f32 -> bf16 (vectorized 8/thread) ----------------
__global__ void conv_f2b(const float* __restrict__ in, u16* __restrict__ out, int n8){
  int i = blockIdx.x * 256 + threadIdx.x;
  if(i >= n8) return;
  f32x4 a = *(const f32x4*)(in + (size_t)i*8);
  f32x4 b = *(const f32x4*)(in + (size_t)i*8 + 4);
  u16x8 o;
  #pragma unroll
  for(int j=0;j<4;j++){ o[j] = f2b(a[j]); o[4+j] = f2b(b[j]); }
  *(u16x8*)(out + (size_t)i*8) = o;
}

// ------------- transpose-convert weights: in R x C f32 -> out C x R bf16 -----
__global__ void tconv(const float* __restrict__ in, u16* __restrict__ out, int R, int C){
  __shared__ __align__(16) float tile[64*68];
  int gc = C >> 6;
  int rt = blockIdx.x / gc, ct = blockIdx.x % gc;
  int r0 = rt*64, c0 = ct*64;
  int tid = threadIdx.x;
  #pragma unroll
  for(int it=0; it<4; it++){
    int idx = tid + it*256;
    int rl = idx >> 4, cseg = idx & 15;
    f32x4 v = *(const f32x4*)(in + (size_t)(r0+rl)*C + c0 + cseg*4);
    *(f32x4*)&tile[rl*68 + cseg*4] = v;
  }
  __syncthreads();
  #pragma unroll
  for(int it=0; it<2; it++){
    int idx = tid + it*256;
    int cl = idx >> 3, rseg = idx & 7;
    u16x8 o;
    #pragma unroll
    for(int j=0;j<8;j++) o[j] = f2b(tile[(rseg*8+j)*68 + cl]);
    *(u16x8*)(out + (size_t)(c0+cl)*R + r0 + rseg*8) = o;
  }
}

// ---------------- GEMM: A(MxK) bf16 row-major, Bt(NxK) bf16 row-major --------
// EPI=0: store bf16 C (MxN).  EPI=1: store f32 C + bias[col].
template<int EPI>
__global__ __launch_bounds__(256,2) void gemm_bt(const u16* __restrict__ A, const u16* __restrict__ Bt,
                                                 void* __restrict__ Cp, const float* __restrict__ bias,
                                                 int M, int N, int K){
  __shared__ __align__(16) u16 As[128*32];
  __shared__ __align__(16) u16 Bs[128*32];
  int tid = threadIdx.x, lane = tid & 63, w = tid >> 6;
  int nb = N >> 7;
  int bm = blockIdx.x / nb, bn = blockIdx.x % nb;
  int m0 = bm*128, n0 = bn*128;
  int wm = (w >> 1)*64, wn = (w & 1)*64;
  int l16 = lane & 15, lg = lane >> 4;
  f32x4 acc[4][4];
  #pragma unroll
  for(int i=0;i<4;i++)
    #pragma unroll
    for(int j=0;j<4;j++) acc[i][j] = (f32x4){0.f,0.f,0.f,0.f};

  for(int kk=0; kk<K; kk+=32){
    #pragma unroll
    for(int it=0; it<2; it++){
      int id = tid + it*256;
      int row = id >> 2, seg = id & 3;
      gl_lds16(A  + (size_t)(m0+row)*K + kk + seg*8, &As[id*8]);
      gl_lds16(Bt + (size_t)(n0+row)*K + kk + seg*8, &Bs[id*8]);
    }
    __syncthreads();
    bf16x8 af[4], bfr[4];
    #pragma unroll
    for(int i=0;i<4;i++) af[i]  = *(const bf16x8*)&As[(wm + i*16 + l16)*32 + lg*8];
    #pragma unroll
    for(int j=0;j<4;j++) bfr[j] = *(const bf16x8*)&Bs[(wn + j*16 + l16)*32 + lg*8];
    #pragma unroll
    for(int i=0;i<4;i++)
      #pragma unroll
      for(int j=0;j<4;j++)
        acc[i][j] = __builtin_amdgcn_mfma_f32_16x16x32_bf16(af[i], bfr[j], acc[i][j], 0,0,0);
    __syncthreads();
  }
  #pragma unroll
  for(int i=0;i<4;i++)
    #pragma unroll
    for(int j=0;j<4;j++){
      int col = n0 + wn + j*16 + l16;
      #pragma unroll
      for(int r=0;r<4;r++){
        int row = m0 + wm + i*16 + lg*4 + r;
        float v = acc[i][j][r];
        if(EPI == 0) ((u16*)Cp)[(size_t)row*N + col] = f2b(v);
        else         ((float*)Cp)[(size_t)row*N + col] = v + bias[col];
      }
    }
}

// scatter qkv -> Q (scaled by 0.125*log2e, +bias) and K (+bias), (b,h,n,d)
__global__ void scatter_qk(const u16* __restrict__ qkv, const float* __restrict__ bqkv,
                           u16* __restrict__ Qs, u16* __restrict__ Ks){
  int v = blockIdx.x * 256 + threadIdx.x;       // 0 .. 1048575
  int which = v >> 19;                          // 0=q, 1=k
  int idx8 = v & 524287;
  int o = idx8 << 3;                            // elem base in (b,h,n,d)
  int b = o >> 21, h = (o >> 17) & 15, n = (o >> 6) & 2047, d0 = o & 63;
  const u16* src = qkv + (size_t)(b*2048 + n)*3072 + which*1024 + h*64 + d0;
  u16x8 raw = *(const u16x8*)src;
  const float* bp = bqkv + which*1024 + h*64 + d0;
  f32x4 b0 = *(const f32x4*)bp, b1 = *(const f32x4*)(bp + 4);
  // fold SCALE * log2(e) into Q so attention can use exp2 directly
  float scale = (which == 0) ? 0.18033688011112042f : 1.0f;
  u16x8 ov;
  #pragma unroll
  for(int j=0;j<4;j++){
    ov[j]   = f2b((b2f(raw[j])   + b0[j]) * scale);
    ov[4+j] = f2b((b2f(raw[4+j]) + b1[j]) * scale);
  }
  u16* dst = (which ? Ks : Qs) + o;
  *(u16x8*)dst = ov;
}

// ---------------- V -> Vt (b,h,d,n) via LDS tile transpose -------------------
__global__ void transpose_v(const u16* __restrict__ qkv, u16* __restrict__ Vt){
  __shared__ __align__(16) u16 tile[64*72];
  int nt = blockIdx.x & 31, bh = blockIdx.x >> 5;
  int b = bh >> 4, h = bh & 15;
  int n0 = nt*64;
  int tid = threadIdx.x;
  const u16* src = qkv + (size_t)(b*2048)*3072 + 2048 + h*64;
  #pragma unroll
  for(int it=0; it<2; it++){
    int idx = tid + it*256;
    int nl = idx >> 3, dseg = idx & 7;
    u16x8 vv = *(const u16x8*)(src + (size_t)(n0+nl)*3072 + dseg*8);
    *(u16x8*)&tile[nl*72 + dseg*8] = vv;
  }
  __syncthreads();
  u16* dst = Vt + (size_t)bh*64*2048;
  #pragma unroll
  for(int it=0; it<2; it++){
    int idx = tid + it*256;
    int dl = idx >> 3, nseg = idx & 7;
    u16x8 o;
    #pragma unroll
    for(int j=0;j<8;j++) o[j] = tile[(nseg*8+j)*72 + dl];
    *(u16x8*)(dst + (size_t)dl*2048 + n0 + nseg*8) = o;
  }
}

// ---------------- fused attention with head-axis softmax ---------------------
// Grid: B * (N/32) * KSPLIT(=4) = 512 blocks (2/CU), 512 threads (8 waves, 2 heads/wave).
// Swapped QK^T (S^T in C-frags) keeps P lane-local in f32; cross-head Z via
// wave-linear f32 zsum in LDS (conflict-free); P relayout for PV via
// cvt_pk + ds_bpermute. Raw barriers (lgkm-only) keep K/V prefetch in flight.
__global__ __launch_bounds__(512,2) void attn_kernel(const u16* __restrict__ Q, const u16* __restrict__ Kg,
                                                     const u16* __restrict__ Vt,
                                                     u16* __restrict__ OpA, u16* __restrict__ OpB){
  __shared__ float zsum[8*1024];   // [wave][slot]  32 KB
  __shared__ float rz[1024];       // [slot]         4 KB
  const int tid = threadIdx.x, lane = tid & 63, w = tid >> 6;
  const int l16 = lane & 15, lg = lane >> 4;
  const int bid = blockIdx.x;
  const int split = bid & 3, qt = (bid >> 2) & 63, b = bid >> 8;
  const int q0 = qt*32;
  const int kbase = split*512;

  const u16* Kh[2]; const u16* Vh[2];
  #pragma unroll
  for(int hh=0;hh<2;hh++){
    int h = w*2 + hh;
    Kh[hh] = Kg + (size_t)(b*16 + h)*2048*64;
    Vh[hh] = Vt + (size_t)(b*16 + h)*64*2048;
  }

  // Q as B-operand frags: qf[hh][qs][dc] : Q[q0+qs*16+l16][dc*32+lg*8 ..]
  bf16x8 qf[2][2][2];
  #pragma unroll
  for(int hh=0;hh<2;hh++){
    int h = w*2 + hh;
    const u16* Qh = Q + ((size_t)(b*16 + h)*2048 + q0)*64;
    #pragma unroll
    for(int qs=0;qs<2;qs++)
      #pragma unroll
      for(int dc=0;dc<2;dc++)
        qf[hh][qs][dc] = *(const bf16x8*)(Qh + (qs*16 + l16)*64 + dc*32 + lg*8);
  }
  // O^T accumulators: Oa[hh][dt][qs]: C[row=d'=4lg+r][col=q=l16]
  f32x4 Oa[2][4][2];
  #pragma unroll
  for(int a=0;a<2;a++)
    #pragma unroll
    for(int d=0;d<4;d++)
      #pragma unroll
      for(int c=0;c<2;c++) Oa[a][d][c] = (f32x4){0.f,0.f,0.f,0.f};

  // K (A-operand) double-buffer: kfb[buf][hh][ks][dc] : K[k+ks*16+l16][dc*32+lg*8..]
  bf16x8 kfb[2][2][2][2];
  #pragma unroll
  for(int hh=0;hh<2;hh++)
    #pragma unroll
    for(int ks=0;ks<2;ks++)
      #pragma unroll
      for(int dc=0;dc<2;dc++)
        kfb[0][hh][ks][dc] = *(const bf16x8*)(Kh[hh] + (size_t)(kbase + ks*16 + l16)*64 + dc*32 + lg*8);

  const int bp0 = ((2*(lg & 1))*16 + l16)*4;   // bpermute byte-index, groups {0,1}... per lg&1
  const int bp1 = bp0 + 64;

  #pragma unroll 2
  for(int kt=0; kt<16; kt++){
    const int cur = kt & 1, nxt = cur ^ 1;
    const int k0 = kbase + kt*32;
    const int k1 = (kt == 15) ? kbase : k0 + 32;   // last prefetch harmless reload

    // V frags for THIS iter (A-operand of PV): consumed at iter end
    bf16x8 vf[2][4];
    #pragma unroll
    for(int hh=0;hh<2;hh++)
      #pragma unroll
      for(int dt=0;dt<4;dt++)
        vf[hh][dt] = *(const bf16x8*)(Vh[hh] + (size_t)(dt*16 + l16)*2048 + k0 + lg*8);

    // S^T = K Q (log2e folded): p[hh][qs][ks][r] = exp2(S), lane-local f32
    float p[2][2][2][4];
    #pragma unroll
    for(int hh=0;hh<2;hh++)
      #pragma unroll
      for(int qs=0;qs<2;qs++)
        #pragma unroll
        for(int ks=0;ks<2;ks++){
          f32x4 S = (f32x4){0.f,0.f,0.f,0.f};
          #pragma unroll
          for(int dc=0;dc<2;dc++)
            S = __builtin_amdgcn_mfma_f32_16x16x32_bf16(kfb[cur][hh][ks][dc], qf[hh][qs][dc], S, 0,0,0);
          #pragma unroll
          for(int r=0;r<4;r++) p[hh][qs][ks][r] = __builtin_amdgcn_exp2f(S[r]);
        }

    // zpart over this wave's 2 heads -> wave-linear slots (stride-1, conflict-free)
    #pragma unroll
    for(int qs=0;qs<2;qs++)
      #pragma unroll
      for(int ks=0;ks<2;ks++)
        #pragma unroll
        for(int r=0;r<4;r++)
          zsum[w*1024 + (qs*2+ks)*256 + r*64 + lane] = p[0][qs][ks][r] + p[1][qs][ks][r];

    // K prefetch for NEXT iter (stays in flight across barriers)
    #pragma unroll
    for(int hh=0;hh<2;hh++)
      #pragma unroll
      for(int ks=0;ks<2;ks++)
        #pragma unroll
        for(int dc=0;dc<2;dc++)
          kfb[nxt][hh][ks][dc] = *(const bf16x8*)(Kh[hh] + (size_t)(k1 + ks*16 + l16)*64 + dc*32 + lg*8);

    lds_barrier();
    // Z-reduce over 8 waves: slot-indexed, stride-1
    #pragma unroll
    for(int rr=0; rr<2; rr++){
      int s = tid + rr*512;
      float z = 0.f;
      #pragma unroll
      for(int wv=0; wv<8; wv++) z += zsum[wv*1024 + s];
      rz[s] = __builtin_amdgcn_rcpf(z);
    }
    lds_barrier();

    // normalize (f32), pack, bpermute-relayout to PV B-frag, MFMA
    #pragma unroll
    for(int hh=0;hh<2;hh++){
      #pragma unroll
      for(int qs=0;qs<2;qs++){
        u32 Wa[2], Wb[2];
        #pragma unroll
        for(int ks=0;ks<2;ks++){
          float pn[4];
          #pragma unroll
          for(int r=0;r<4;r++)
            pn[r] = p[hh][qs][ks][r] * rz[(qs*2+ks)*256 + r*64 + lane];
          Wa[ks] = cvt_pk_bf16(pn[0], pn[1]);
          Wb[ks] = cvt_pk_bf16(pn[2], pn[3]);
        }
        bool lo = (lg < 2);
        u32 t0a = __builtin_amdgcn_ds_bpermute(bp0, (int)Wa[0]);
        u32 t0b = __builtin_amdgcn_ds_bpermute(bp0, (int)Wa[1]);
        u32 t1a = __builtin_amdgcn_ds_bpermute(bp0, (int)Wb[0]);
        u32 t1b = __builtin_amdgcn_ds_bpermute(bp0, (int)Wb[1]);
        u32 t2a = __builtin_amdgcn_ds_bpermute(bp1, (int)Wa[0]);
        u32 t2b = __builtin_amdgcn_ds_bpermute(bp1, (int)Wa[1]);
        u32 t3a = __builtin_amdgcn_ds_bpermute(bp1, (int)Wb[0]);
        u32 t3b = __builtin_amdgcn_ds_bpermute(bp1, (int)Wb[1]);
        union { u32 wd[4]; bf16x8 v; } U;
        U.wd[0] = lo ? t0a : t0b;
        U.wd[1] = lo ? t1a : t1b;
        U.wd[2] = lo ? t2a : t2b;
        U.wd[3] = lo ? t3a : t3b;
        #pragma unroll
        for(int dt=0;dt<4;dt++)
          Oa[hh][dt][qs] = __builtin_amdgcn_mfma_f32_16x16x32_bf16(vf[hh][dt], U.v, Oa[hh][dt][qs], 0,0,0);
      }
    }
  }
  // epilogue: O^T frags -> Op[split] (b, n, h*64+d) bf16; pack 4 contiguous cols
  u16* Ob = (split == 3) ? OpB : (OpA + (size_t)split*4194304);
  #pragma unroll
  for(int hh=0;hh<2;hh++){
    int h = w*2 + hh;
    #pragma unroll
    for(int dt=0;dt<4;dt++)
      #pragma unroll
      for(int qs=0;qs<2;qs++){
        int row = q0 + qs*16 + l16;
        int col = h*64 + dt*16 + lg*4;
        u32x2 pk2;
        pk2[0] = cvt_pk_bf16(Oa[hh][dt][qs][0], Oa[hh][dt][qs][1]);
        pk2[1] = cvt_pk_bf16(Oa[hh][dt][qs][2], Oa[hh][dt][qs][3]);
        *(u32x2*)(Ob + (size_t)(b*2048 + row)*1024 + col) = pk2;
      }
  }
}

// ---------------- combine k-split partials -> bf16 w_avg ---------------------
__global__ void combine4(const u16* __restrict__ a, const u16* __restrict__ b,
                         const u16* __restrict__ c, const u16* __restrict__ d,
                         u16* __restrict__ o){
  int i = blockIdx.x * 256 + threadIdx.x;
  u16x8 va = ((const u16x8*)a)[i], vb = ((const u16x8*)b)[i];
  u16x8 vc = ((const u16x8*)c)[i], vd = ((const u16x8*)d)[i];
  u16x8 vo;
  #pragma unroll
  for(int j=0;j<8;j++) vo[j] = f2b((b2f(va[j]) + b2f(vb[j])) + (b2f(vc[j]) + b2f(vd[j])));
  ((u16x8*)o)[i] = vo;
}

extern "C" void kernel_launch(void* const* d_in, const int* in_sizes, int n_in,
                              void* d_out, int out_size, void* d_ws, size_t ws_size,
                              hipStream_t stream){
  const float* x      = (const float*)d_in[0];
  const float* w_qkv  = (const float*)d_in[1];
  const float* b_qkv  = (const float*)d_in[2];
  const float* w_proj = (const float*)d_in[3];
  const float* b_proj = (const float*)d_in[4];
  float* out = (float*)d_out;
  char* ws = (char*)d_ws;

  u16* xb   = (u16*)(ws);                 // 8.4 MB  (free after gemm<0>; reused as Op3)
  u16* wqT  = (u16*)(ws + 8388608);       // 6.3 MB
  u16* wpT  = (u16*)(ws + 14680064);      // 2.1 MB
  u16* Qs   = (u16*)(ws + 16777216);      // 8.4 MB  (free after attn; reused as w_avg)
  u16* Ks   = (u16*)(ws + 25165824);      // 8.4 MB
  u16* Vt   = (u16*)(ws + 33554432);      // 8.4 MB
  u16* qkvb = (u16*)(ws + 41943040);      // 25.2 MB (free after scatter/transpose; Op0..2)
  u16* Op0  = qkvb;
  u16* Op1  = qkvb + 4194304;
  u16* Op2  = qkvb + 2*4194304;
  u16* Op3  = xb;
  u16* wavg = Qs;

  conv_f2b<<<2048, 256, 0, stream>>>(x, xb, 524288);
  tconv<<<768, 256, 0, stream>>>(w_qkv, wqT, 1024, 3072);
  tconv<<<256, 256, 0, stream>>>(w_proj, wpT, 1024, 1024);
  gemm_bt<0><<<768, 256, 0, stream>>>(xb, wqT, (void*)qkvb, nullptr, 4096, 3072, 1024);
  scatter_qk<<<4096, 256, 0, stream>>>(qkvb, b_qkv, Qs, Ks);
  transpose_v<<<1024, 256, 0, stream>>>(qkvb, Vt);
  attn_kernel<<<512, 512, 0, stream>>>(Qs, Ks, Vt, Op0, Op3);
  combine4<<<2048, 256, 0, stream>>>(Op0, Op1, Op2, Op3, wavg);
  gemm_bt<1><<<256, 256, 0, stream>>>(wavg, wpT, (void*)out, b_proj, 4096, 1024, 1024);
}

// Round 9
// 215.578 us; speedup vs baseline: 1.0612x; 1.0612x over previous
//
#include <hip/hip_runtime.h>

typedef unsigned short u16;
typedef unsigned int u32;
typedef __attribute__((ext_vector_type(8))) short bf16x8;
typedef __attribute__((ext_vector_type(4))) float f32x4;
typedef __attribute__((ext_vector_type(8))) u16 u16x8;
typedef __attribute__((ext_vector_type(2))) u32 u32x2;

__device__ __forceinline__ u16 f2b(float f){
  u32 u = __float_as_uint(f);
  u32 r = (u + 0x7fffu + ((u >> 16) & 1u)) >> 16;
  return (u16)r;
}
__device__ __forceinline__ float b2f(u16 h){ return __uint_as_float(((u32)h) << 16); }
// packed f32x2 -> bf16x2 (RNE), lo=src0 hi=src1
__device__ __forceinline__ u32 cvt_pk_bf16(float lo, float hi){
  u32 r; asm("v_cvt_pk_bf16_f32 %0, %1, %2" : "=v"(r) : "v"(lo), "v"(hi)); return r;
}
// LDS-visibility barrier WITHOUT vmcnt drain (keeps global prefetches in flight)
__device__ __forceinline__ void lds_barrier(){
  asm volatile("s_waitcnt lgkmcnt(0)" ::: "memory");
  __builtin_amdgcn_s_barrier();
  asm volatile("" ::: "memory");
}

typedef const __attribute__((address_space(1))) void gvoid;
typedef __attribute__((address_space(3))) void svoid;
__device__ __forceinline__ void gl_lds16(const void* g, void* l){
  __builtin_amdgcn_global_load_lds((gvoid*)g, (svoid*)l, 16, 0, 0);
}

// ---------------- convert x f32 -> bf16 (vectorized 8/thread) ----------------
__global__ void conv_f2b(const float* __restrict__ in, u16* __restrict__ out, int n8){
  int i = blockIdx.x * 256 + threadIdx.x;
  if(i >= n8) return;
  f32x4 a = *(const f32x4*)(in + (size_t)i*8);
  f32x4 b = *(const f32x4*)(in + (size_t)i*8 + 4);
  u16x8 o;
  #pragma unroll
  for(int j=0;j<4;j++){ o[j] = f2b(a[j]); o[4+j] = f2b(b[j]); }
  *(u16x8*)(out + (size_t)i*8) = o;
}

// ------------- transpose-convert weights: in R x C f32 -> out C x R bf16 -----
__global__ void tconv(const float* __restrict__ in, u16* __restrict__ out, int R, int C){
  __shared__ __align__(16) float tile[64*68];
  int gc = C >> 6;
  int rt = blockIdx.x / gc, ct = blockIdx.x % gc;
  int r0 = rt*64, c0 = ct*64;
  int tid = threadIdx.x;
  #pragma unroll
  for(int it=0; it<4; it++){
    int idx = tid + it*256;
    int rl = idx >> 4, cseg = idx & 15;
    f32x4 v = *(const f32x4*)(in + (size_t)(r0+rl)*C + c0 + cseg*4);
    *(f32x4*)&tile[rl*68 + cseg*4] = v;
  }
  __syncthreads();
  #pragma unroll
  for(int it=0; it<2; it++){
    int idx = tid + it*256;
    int cl = idx >> 3, rseg = idx & 7;
    u16x8 o;
    #pragma unroll
    for(int j=0;j<8;j++) o[j] = f2b(tile[(rseg*8+j)*68 + cl]);
    *(u16x8*)(out + (size_t)(c0+cl)*R + r0 + rseg*8) = o;
  }
}

// ---------------- GEMM: A(MxK) bf16 row-major, Bt(NxK) bf16 row-major --------
// EPI=0: store bf16 C (MxN).  EPI=1: store f32 C + bias[col].
template<int EPI>
__global__ __launch_bounds__(256,2) void gemm_bt(const u16* __restrict__ A, const u16* __restrict__ Bt,
                                                 void* __restrict__ Cp, const float* __restrict__ bias,
                                                 int M, int N, int K){
  __shared__ __align__(16) u16 As[128*32];
  __shared__ __align__(16) u16 Bs[128*32];
  int tid = threadIdx.x, lane = tid & 63, w = tid >> 6;
  int nb = N >> 7;
  int bm = blockIdx.x / nb, bn = blockIdx.x % nb;
  int m0 = bm*128, n0 = bn*128;
  int wm = (w >> 1)*64, wn = (w & 1)*64;
  int l16 = lane & 15, lg = lane >> 4;
  f32x4 acc[4][4];
  #pragma unroll
  for(int i=0;i<4;i++)
    #pragma unroll
    for(int j=0;j<4;j++) acc[i][j] = (f32x4){0.f,0.f,0.f,0.f};

  for(int kk=0; kk<K; kk+=32){
    #pragma unroll
    for(int it=0; it<2; it++){
      int id = tid + it*256;
      int row = id >> 2, seg = id & 3;
      gl_lds16(A  + (size_t)(m0+row)*K + kk + seg*8, &As[id*8]);
      gl_lds16(Bt + (size_t)(n0+row)*K + kk + seg*8, &Bs[id*8]);
    }
    __syncthreads();
    bf16x8 af[4], bfr[4];
    #pragma unroll
    for(int i=0;i<4;i++) af[i]  = *(const bf16x8*)&As[(wm + i*16 + l16)*32 + lg*8];
    #pragma unroll
    for(int j=0;j<4;j++) bfr[j] = *(const bf16x8*)&Bs[(wn + j*16 + l16)*32 + lg*8];
    #pragma unroll
    for(int i=0;i<4;i++)
      #pragma unroll
      for(int j=0;j<4;j++)
        acc[i][j] = __builtin_amdgcn_mfma_f32_16x16x32_bf16(af[i], bfr[j], acc[i][j], 0,0,0);
    __syncthreads();
  }
  #pragma unroll
  for(int i=0;i<4;i++)
    #pragma unroll
    for(int j=0;j<4;j++){
      int col = n0 + wn + j*16 + l16;
      #pragma unroll
      for(int r=0;r<4;r++){
        int row = m0 + wm + i*16 + lg*4 + r;
        float v = acc[i][j][r];
        if(EPI == 0) ((u16*)Cp)[(size_t)row*N + col] = f2b(v);
        else         ((float*)Cp)[(size_t)row*N + col] = v + bias[col];
      }
    }
}

// ------- QKV GEMM with fused scatter epilogue: M=4096,N=3072,K=1024 ----------
// cols [0,1024): Q -> Qs (b,h,n,d), (v+bias)*SCALE*log2e
// cols [1024,2048): K -> Ks (b,h,n,d), v+bias
// cols [2048,3072): V -> Vout row-major qkv layout (row*3072+col), v+bias
__global__ __launch_bounds__(256,2) void gemm_qkv(const u16* __restrict__ A, const u16* __restrict__ Bt,
                                                  const float* __restrict__ bias,
                                                  u16* __restrict__ Qs, u16* __restrict__ Ks,
                                                  u16* __restrict__ Vout){
  const int N = 3072, K = 1024;
  __shared__ __align__(16) u16 As[128*32];
  __shared__ __align__(16) u16 Bs[128*32];
  int tid = threadIdx.x, lane = tid & 63, w = tid >> 6;
  int nb = N >> 7;
  int bm = blockIdx.x / nb, bn = blockIdx.x % nb;
  int m0 = bm*128, n0 = bn*128;
  int wm = (w >> 1)*64, wn = (w & 1)*64;
  int l16 = lane & 15, lg = lane >> 4;
  f32x4 acc[4][4];
  #pragma unroll
  for(int i=0;i<4;i++)
    #pragma unroll
    for(int j=0;j<4;j++) acc[i][j] = (f32x4){0.f,0.f,0.f,0.f};

  for(int kk=0; kk<K; kk+=32){
    #pragma unroll
    for(int it=0; it<2; it++){
      int id = tid + it*256;
      int row = id >> 2, seg = id & 3;
      gl_lds16(A  + (size_t)(m0+row)*K + kk + seg*8, &As[id*8]);
      gl_lds16(Bt + (size_t)(n0+row)*K + kk + seg*8, &Bs[id*8]);
    }
    __syncthreads();
    bf16x8 af[4], bfr[4];
    #pragma unroll
    for(int i=0;i<4;i++) af[i]  = *(const bf16x8*)&As[(wm + i*16 + l16)*32 + lg*8];
    #pragma unroll
    for(int j=0;j<4;j++) bfr[j] = *(const bf16x8*)&Bs[(wn + j*16 + l16)*32 + lg*8];
    #pragma unroll
    for(int i=0;i<4;i++)
      #pragma unroll
      for(int j=0;j<4;j++)
        acc[i][j] = __builtin_amdgcn_mfma_f32_16x16x32_bf16(af[i], bfr[j], acc[i][j], 0,0,0);
    __syncthreads();
  }
  #pragma unroll
  for(int i=0;i<4;i++)
    #pragma unroll
    for(int j=0;j<4;j++){
      int col = n0 + wn + j*16 + l16;
      int which = col >> 10;            // 0=Q 1=K 2=V (uniform per 16-lane group)
      int hd = col & 1023;
      int h = hd >> 6, d = hd & 63;
      float bcol = bias[col];
      float scale = (which == 0) ? 0.18033688011112042f : 1.0f;
      #pragma unroll
      for(int r=0;r<4;r++){
        int row = m0 + wm + i*16 + lg*4 + r;       // row = b*2048 + n
        float v = (acc[i][j][r] + bcol) * scale;
        if(which == 2){
          Vout[(size_t)row*3072 + col] = f2b(v);
        } else {
          int b = row >> 11, n = row & 2047;
          u16* dst = (which ? Ks : Qs);
          dst[((size_t)(b*16 + h)*2048 + n)*64 + d] = f2b(v);
        }
      }
    }
}

// ---------------- V -> Vt (b,h,d,n) via LDS tile transpose -------------------
__global__ void transpose_v(const u16* __restrict__ qkv, u16* __restrict__ Vt){
  __shared__ __align__(16) u16 tile[64*72];
  int nt = blockIdx.x & 31, bh = blockIdx.x >> 5;
  int b = bh >> 4, h = bh & 15;
  int n0 = nt*64;
  int tid = threadIdx.x;
  const u16* src = qkv + (size_t)(b*2048)*3072 + 2048 + h*64;
  #pragma unroll
  for(int it=0; it<2; it++){
    int idx = tid + it*256;
    int nl = idx >> 3, dseg = idx & 7;
    u16x8 vv = *(const u16x8*)(src + (size_t)(n0+nl)*3072 + dseg*8);
    *(u16x8*)&tile[nl*72 + dseg*8] = vv;
  }
  __syncthreads();
  u16* dst = Vt + (size_t)bh*64*2048;
  #pragma unroll
  for(int it=0; it<2; it++){
    int idx = tid + it*256;
    int dl = idx >> 3, nseg = idx & 7;
    u16x8 o;
    #pragma unroll
    for(int j=0;j<8;j++) o[j] = tile[(nseg*8+j)*72 + dl];
    *(u16x8*)(dst + (size_t)dl*2048 + n0 + nseg*8) = o;
  }
}

// ---------------- fused attention with head-axis softmax ---------------------
// Grid: B * (N/32) * KSPLIT(=2) = 256 blocks, 512 threads (8 waves, 2 heads/wave).
// Swapped QK^T (S^T in C-frags) keeps P lane-local in f32; cross-head Z via
// wave-linear f32 zsum in LDS (conflict-free); P relayout for PV via
// cvt_pk + ds_bpermute. Raw barriers (lgkm-only) keep K/V prefetch in flight.
__global__ __launch_bounds__(512,2) void attn_kernel(const u16* __restrict__ Q, const u16* __restrict__ Kg,
                                                     const u16* __restrict__ Vt, u16* __restrict__ Op){
  __shared__ float zsum[8*1024];   // [wave][slot]  32 KB
  __shared__ float rz[1024];       // [slot]         4 KB
  const int tid = threadIdx.x, lane = tid & 63, w = tid >> 6;
  const int l16 = lane & 15, lg = lane >> 4;
  const int bid = blockIdx.x;
  const int split = bid & 1, qt = (bid >> 1) & 63, b = bid >> 7;
  const int q0 = qt*32;
  const int kbase = split*1024;

  const u16* Kh[2]; const u16* Vh[2];
  #pragma unroll
  for(int hh=0;hh<2;hh++){
    int h = w*2 + hh;
    Kh[hh] = Kg + (size_t)(b*16 + h)*2048*64;
    Vh[hh] = Vt + (size_t)(b*16 + h)*64*2048;
  }

  // Q as B-operand frags: qf[hh][qs][dc] : Q[q0+qs*16+l16][dc*32+lg*8 ..]
  bf16x8 qf[2][2][2];
  #pragma unroll
  for(int hh=0;hh<2;hh++){
    int h = w*2 + hh;
    const u16* Qh = Q + ((size_t)(b*16 + h)*2048 + q0)*64;
    #pragma unroll
    for(int qs=0;qs<2;qs++)
      #pragma unroll
      for(int dc=0;dc<2;dc++)
        qf[hh][qs][dc] = *(const bf16x8*)(Qh + (qs*16 + l16)*64 + dc*32 + lg*8);
  }
  // O^T accumulators: Oa[hh][dt][qs]: C[row=d'=4lg+r][col=q=l16]
  f32x4 Oa[2][4][2];
  #pragma unroll
  for(int a=0;a<2;a++)
    #pragma unroll
    for(int d=0;d<4;d++)
      #pragma unroll
      for(int c=0;c<2;c++) Oa[a][d][c] = (f32x4){0.f,0.f,0.f,0.f};

  // K (A-operand) double-buffer: kfb[buf][hh][ks][dc] : K[k+ks*16+l16][dc*32+lg*8..]
  bf16x8 kfb[2][2][2][2];
  #pragma unroll
  for(int hh=0;hh<2;hh++)
    #pragma unroll
    for(int ks=0;ks<2;ks++)
      #pragma unroll
      for(int dc=0;dc<2;dc++)
        kfb[0][hh][ks][dc] = *(const bf16x8*)(Kh[hh] + (size_t)(kbase + ks*16 + l16)*64 + dc*32 + lg*8);

  const int bp0 = ((2*(lg & 1))*16 + l16)*4;   // bpermute byte-index, groups {0,1}... per lg&1
  const int bp1 = bp0 + 64;

  #pragma unroll 2
  for(int kt=0; kt<32; kt++){
    const int cur = kt & 1, nxt = cur ^ 1;
    const int k0 = kbase + kt*32;
    const int k1 = (kt == 31) ? kbase : k0 + 32;   // last prefetch harmless reload

    // V frags for THIS iter (A-operand of PV): consumed at iter end
    bf16x8 vf[2][4];
    #pragma unroll
    for(int hh=0;hh<2;hh++)
      #pragma unroll
      for(int dt=0;dt<4;dt++)
        vf[hh][dt] = *(const bf16x8*)(Vh[hh] + (size_t)(dt*16 + l16)*2048 + k0 + lg*8);

    // S^T = K Q (log2e folded): p[hh][qs][ks][r] = exp2(S), lane-local f32
    float p[2][2][2][4];
    #pragma unroll
    for(int hh=0;hh<2;hh++)
      #pragma unroll
      for(int qs=0;qs<2;qs++)
        #pragma unroll
        for(int ks=0;ks<2;ks++){
          f32x4 S = (f32x4){0.f,0.f,0.f,0.f};
          #pragma unroll
          for(int dc=0;dc<2;dc++)
            S = __builtin_amdgcn_mfma_f32_16x16x32_bf16(kfb[cur][hh][ks][dc], qf[hh][qs][dc], S, 0,0,0);
          #pragma unroll
          for(int r=0;r<4;r++) p[hh][qs][ks][r] = __builtin_amdgcn_exp2f(S[r]);
        }

    // zpart over this wave's 2 heads -> wave-linear slots (stride-1, conflict-free)
    #pragma unroll
    for(int qs=0;qs<2;qs++)
      #pragma unroll
      for(int ks=0;ks<2;ks++)
        #pragma unroll
        for(int r=0;r<4;r++)
          zsum[w*1024 + (qs*2+ks)*256 + r*64 + lane] = p[0][qs][ks][r] + p[1][qs][ks][r];

    // K prefetch for NEXT iter (stays in flight across barriers)
    #pragma unroll
    for(int hh=0;hh<2;hh++)
      #pragma unroll
      for(int ks=0;ks<2;ks++)
        #pragma unroll
        for(int dc=0;dc<2;dc++)
          kfb[nxt][hh][ks][dc] = *(const bf16x8*)(Kh[hh] + (size_t)(k1 + ks*16 + l16)*64 + dc*32 + lg*8);

    lds_barrier();
    // Z-reduce over 8 waves: slot-indexed, stride-1
    #pragma unroll
    for(int rr=0; rr<2; rr++){
      int s = tid + rr*512;
      float z = 0.f;
      #pragma unroll
      for(int wv=0; wv<8; wv++) z += zsum[wv*1024 + s];
      rz[s] = __builtin_amdgcn_rcpf(z);
    }
    lds_barrier();

    // normalize (f32), pack, bpermute-relayout to PV B-frag, MFMA
    #pragma unroll
    for(int hh=0;hh<2;hh++){
      #pragma unroll
      for(int qs=0;qs<2;qs++){
        u32 Wa[2], Wb[2];
        #pragma unroll
        for(int ks=0;ks<2;ks++){
          float pn[4];
          #pragma unroll
          for(int r=0;r<4;r++)
            pn[r] = p[hh][qs][ks][r] * rz[(qs*2+ks)*256 + r*64 + lane];
          Wa[ks] = cvt_pk_bf16(pn[0], pn[1]);
          Wb[ks] = cvt_pk_bf16(pn[2], pn[3]);
        }
        bool lo = (lg < 2);
        u32 t0a = __builtin_amdgcn_ds_bpermute(bp0, (int)Wa[0]);
        u32 t0b = __builtin_amdgcn_ds_bpermute(bp0, (int)Wa[1]);
        u32 t1a = __builtin_amdgcn_ds_bpermute(bp0, (int)Wb[0]);
        u32 t1b = __builtin_amdgcn_ds_bpermute(bp0, (int)Wb[1]);
        u32 t2a = __builtin_amdgcn_ds_bpermute(bp1, (int)Wa[0]);
        u32 t2b = __builtin_amdgcn_ds_bpermute(bp1, (int)Wa[1]);
        u32 t3a = __builtin_amdgcn_ds_bpermute(bp1, (int)Wb[0]);
        u32 t3b = __builtin_amdgcn_ds_bpermute(bp1, (int)Wb[1]);
        union { u32 wd[4]; bf16x8 v; } U;
        U.wd[0] = lo ? t0a : t0b;
        U.wd[1] = lo ? t1a : t1b;
        U.wd[2] = lo ? t2a : t2b;
        U.wd[3] = lo ? t3a : t3b;
        #pragma unroll
        for(int dt=0;dt<4;dt++)
          Oa[hh][dt][qs] = __builtin_amdgcn_mfma_f32_16x16x32_bf16(vf[hh][dt], U.v, Oa[hh][dt][qs], 0,0,0);
      }
    }
  }
  // epilogue: O^T frags -> Op[split] (b, n, h*64+d) bf16; pack 4 contiguous cols
  u16* Ob = Op + (size_t)split*4194304;
  #pragma unroll
  for(int hh=0;hh<2;hh++){
    int h = w*2 + hh;
    #pragma unroll
    for(int dt=0;dt<4;dt++)
      #pragma unroll
      for(int qs=0;qs<2;qs++){
        int row = q0 + qs*16 + l16;
        int col = h*64 + dt*16 + lg*4;
        u32x2 pk2;
        pk2[0] = cvt_pk_bf16(Oa[hh][dt][qs][0], Oa[hh][dt][qs][1]);
        pk2[1] = cvt_pk_bf16(Oa[hh][dt][qs][2], Oa[hh][dt][qs][3]);
        *(u32x2*)(Ob + (size_t)(b*2048 + row)*1024 + col) = pk2;
      }
  }
}

// ---------------- combine k-split partials -> bf16 w_avg ---------------------
__global__ void combine2(const u16* __restrict__ a, const u16* __restrict__ b, u16* __restrict__ o){
  int i = blockIdx.x * 256 + threadIdx.x;
  u16x8 va = ((const u16x8*)a)[i], vb = ((const u16x8*)b)[i];
  u16x8 vo;
  #pragma unroll
  for(int j=0;j<8;j++) vo[j] = f2b(b2f(va[j]) + b2f(vb[j]));
  ((u16x8*)o)[i] = vo;
}

extern "C" void kernel_launch(void* const* d_in, const int* in_sizes, int n_in,
                              void* d_out, int out_size, void* d_ws, size_t ws_size,
                              hipStream_t stream){
  const float* x      = (const float*)d_in[0];
  const float* w_qkv  = (const float*)d_in[1];
  const float* b_qkv  = (const float*)d_in[2];
  const float* w_proj = (const float*)d_in[3];
  const float* b_proj = (const float*)d_in[4];
  float* out = (float*)d_out;
  char* ws = (char*)d_ws;

  u16* xb   = (u16*)(ws);                 // 8.4 MB  (reused as w_avg later)
  u16* wqT  = (u16*)(ws + 8388608);       // 6.3 MB
  u16* wpT  = (u16*)(ws + 14680064);      // 2.1 MB
  u16* Qs   = (u16*)(ws + 16777216);      // 8.4 MB
  u16* Ks   = (u16*)(ws + 25165824);      // 8.4 MB
  u16* Vt   = (u16*)(ws + 33554432);      // 8.4 MB
  u16* qkvb = (u16*)(ws + 41943040);      // 25.2 MB (V third used; reused as Op0/Op1)
  u16* Op0  = qkvb;
  u16* Op1  = qkvb + 4194304;
  u16* wavg = xb;

  conv_f2b<<<2048, 256, 0, stream>>>(x, xb, 524288);
  tconv<<<768, 256, 0, stream>>>(w_qkv, wqT, 1024, 3072);
  tconv<<<256, 256, 0, stream>>>(w_proj, wpT, 1024, 1024);
  gemm_qkv<<<768, 256, 0, stream>>>(xb, wqT, b_qkv, Qs, Ks, qkvb);
  transpose_v<<<1024, 256, 0, stream>>>(qkvb, Vt);
  attn_kernel<<<256, 512, 0, stream>>>(Qs, Ks, Vt, Op0);
  combine2<<<2048, 256, 0, stream>>>(Op0, Op1, wavg);
  gemm_bt<1><<<256, 256, 0, stream>>>(wavg, wpT, (void*)out, b_proj, 4096, 1024, 1024);
}